// Round 1
// baseline (282.535 us; speedup 1.0000x reference)
//
#include <hip/hip_runtime.h>

// Adaptive avg-pool 28x28 -> 7x7, channel-last output.
// x: [B=32, C=2048, 28, 28] fp32 ; out: [B, 49, C] fp32
// 28/7 == 4: each bin is an aligned 4x4 patch; each aligned float4 along w
// lies entirely inside one w-bin.
//
// Block = (b, 64-channel tile), 4 waves.
//   - wave w sequentially processes images c0+16w .. c0+16w+15
//   - per image: wave loads 196 float4 (3136 B contiguous), hsum -> wave-
//     PRIVATE scratch (no barrier needed: intra-wave LDS ordering is handled
//     by compiler lgkmcnt waits); 49 lanes combine 4 row-partials -> res.
//   - scratch is double-buffered (it&1) to kill the WAR stall between
//     iterations; next image's global loads are register-prefetched so
//     global_load_dwordx4 stays in flight under the LDS/reduce chain.
//   - ONE __syncthreads() total (before epilogue): res is the only
//     cross-wave data.
//   - epilogue: wave w stores rows p = w, w+4, ... as 256 B contiguous,
//     256 B-aligned stores (perfect write coalescing).

#define CH 2048
#define OUT_PER_B (49 * CH)

__device__ __forceinline__ float hsum4(float4 v) {
    return (v.x + v.y) + (v.z + v.w);
}

__global__ __launch_bounds__(256) void upp_pool_kernel(const float* __restrict__ x,
                                                       float* __restrict__ out) {
    __shared__ float scratch[4][2][200];   // [wave][parity][row-partials]
    __shared__ float res[49][65];          // [bin][channel-slot], +1 pad

    const int wave = threadIdx.x >> 6;
    const int lane = threadIdx.x & 63;
    const int b    = blockIdx.x >> 5;          // 32 channel-tiles per b
    const int c0   = (blockIdx.x & 31) * 64;   // channel tile base

    const float* imgBase = x + ((size_t)b * CH + c0 + wave * 16) * 784;

    // bin index for lanes 0..48
    const int bi   = lane / 7;
    const int bj   = lane - bi * 7;
    const int bofs = bi * 28 + bj;

    // prologue: prefetch image 0 into registers
    float4 a0, a1, a2, a3;
    {
        const float4* img = (const float4*)imgBase;
        a0 = img[lane];
        a1 = img[lane + 64];
        a2 = img[lane + 128];
        a3 = (lane < 4) ? img[192 + lane] : make_float4(0.f, 0.f, 0.f, 0.f);
    }

#pragma unroll
    for (int it = 0; it < 16; ++it) {
        // prefetch image it+1 while we reduce image it
        float4 b0, b1, b2, b3;
        b0 = b1 = b2 = b3 = make_float4(0.f, 0.f, 0.f, 0.f);
        if (it < 15) {
            const float4* img = (const float4*)(imgBase + (size_t)(it + 1) * 784);
            b0 = img[lane];
            b1 = img[lane + 64];
            b2 = img[lane + 128];
            if (lane < 4) b3 = img[192 + lane];
        }

        float* L = scratch[wave][it & 1];
        L[lane]       = hsum4(a0);
        L[lane + 64]  = hsum4(a1);
        L[lane + 128] = hsum4(a2);
        if (lane < 4) L[192 + lane] = hsum4(a3);

        // wave-private LDS: write->read ordered by lgkmcnt, no barrier
        if (lane < 49) {
            const float s = (L[bofs] + L[bofs + 7]) +
                            (L[bofs + 14] + L[bofs + 21]);
            res[lane][wave * 16 + it] = s * (1.0f / 16.0f);
        }

        a0 = b0; a1 = b1; a2 = b2; a3 = b3;
    }

    __syncthreads();   // res fully written by all waves

    // Epilogue: coalesced 256 B row stores.
    float* outBase = out + (size_t)b * OUT_PER_B + c0;
#pragma unroll
    for (int p = wave; p < 49; p += 4) {
        outBase[(size_t)p * CH + lane] = res[p][lane];
    }
}

extern "C" void kernel_launch(void* const* d_in, const int* in_sizes, int n_in,
                              void* d_out, int out_size, void* d_ws, size_t ws_size,
                              hipStream_t stream) {
    const float* x = (const float*)d_in[0];
    float* out = (float*)d_out;

    // 32 batches x 32 channel-tiles (64 ch each) = 1024 blocks
    upp_pool_kernel<<<1024, 256, 0, stream>>>(x, out);
}